// Round 1
// baseline (1238.503 us; speedup 1.0000x reference)
//
#include <hip/hip_runtime.h>

#define NN   100000
#define EE   1600000
#define GG   64
#define HIDC 128
#define LL   4

typedef unsigned short u16;
typedef unsigned int   u32;
typedef __attribute__((ext_vector_type(8))) short short8v;
typedef __attribute__((ext_vector_type(4))) float f32x4;

__device__ __forceinline__ u16 f2bf(float f){
    u32 u = __float_as_uint(f);
    u32 r = (u + 0x7fffu + ((u >> 16) & 1u)) >> 16;
    return (u16)r;
}

// ---------------- weight packing: fp32 [K=128][M] -> bf16 MFMA B-frag order ----
// dst element index within a matrix: ct*2048 + kt*512 + lane*8 + j
// holds W[k = kt*32 + (lane>>4)*8 + j][c = ct*16 + (lane&15)]
__global__ __launch_bounds__(256) void k_pack(const float* lin_w, const float* bases_w,
                                              const float* comb_w, u16* wpack){
    int t = blockIdx.x * 256 + threadIdx.x;
    if (t >= 98304) return;
    int li, m, isLin;
    if (t < 16384){ isLin = 1; li = 0; m = t; }
    else { isLin = 0; int u = t - 16384; li = u / 20480; m = u % 20480; }
    int j = m & 7, lane = (m >> 3) & 63, kt = (m >> 9) & 3, ct = m >> 11;
    int k = kt * 32 + ((lane >> 4) << 3) + j;
    int c = ct * 16 + (lane & 15);
    float v;
    if (isLin) v = lin_w[k * HIDC + c];
    else       v = (c < 64) ? bases_w[(li * HIDC + k) * 64 + c]
                            : comb_w[(li * HIDC + k) * 96 + (c - 64)];
    wpack[t] = f2bf(v);
}

// ---------------- CSR build ----------------
__global__ __launch_bounds__(256) void k_hist(const int* dst, int* deg){
    int e = blockIdx.x * 256 + threadIdx.x;
    if (e < EE) atomicAdd(&deg[dst[e]], 1);
}

__global__ __launch_bounds__(256) void k_scan1(const int* deg, int* bsums){
    __shared__ int sd[256];
    int b = blockIdx.x, t = threadIdx.x, base = b * 1024;
    int s = 0;
    for (int j = 0; j < 4; ++j){ int i = base + j * 256 + t; if (i < NN) s += deg[i]; }
    sd[t] = s; __syncthreads();
    for (int o = 128; o > 0; o >>= 1){ if (t < o) sd[t] += sd[t + o]; __syncthreads(); }
    if (t == 0) bsums[b] = sd[0];
}

__global__ void k_scan2(const int* bsums, int* boffs, int nb){
    if (threadIdx.x == 0 && blockIdx.x == 0){
        int run = 0;
        for (int b = 0; b < nb; ++b){ boffs[b] = run; run += bsums[b]; }
    }
}

__global__ __launch_bounds__(256) void k_scan3(const int* deg, const int* boffs, int* rowptr){
    __shared__ int ss[256];
    int b = blockIdx.x, t = threadIdx.x, base = b * 1024;
    int v[4]; int s = 0;
    for (int j = 0; j < 4; ++j){ int i = base + t * 4 + j; v[j] = (i < NN) ? deg[i] : 0; s += v[j]; }
    ss[t] = s; __syncthreads();
    for (int o = 1; o < 256; o <<= 1){
        int val = 0; if (t >= o) val = ss[t - o];
        __syncthreads(); ss[t] += val; __syncthreads();
    }
    int run = boffs[b] + (ss[t] - s);
    for (int j = 0; j < 4; ++j){ int i = base + t * 4 + j; if (i < NN) rowptr[i] = run; run += v[j]; }
    if (b == 0 && t == 0) rowptr[NN] = EE;
}

__global__ __launch_bounds__(256) void k_scatter(const int* src, const int* dst,
                                                 const int* rowptr, int* fill, int* ssrc){
    int e = blockIdx.x * 256 + threadIdx.x;
    if (e < EE){
        int d = dst[e];
        int pos = rowptr[d] + atomicAdd(&fill[d], 1);
        ssrc[pos] = src[e];
    }
}

// ---------------- GEMMs (bf16 MFMA 16x16x32, K=128) ----------------
// h = x @ lin_w + lin_b ; writes fp32 h (d_out) and bf16 copy hbf
__global__ __launch_bounds__(256) void k_gemm_lin(const float* x, const u16* wp,
                                                  const float* lin_b, float* hout, u16* hbf){
    int lane = threadIdx.x & 63, wv = threadIdx.x >> 6;
    int n0 = blockIdx.x * 16;
    int l15 = lane & 15, lhi = lane >> 4;
    const float* xr = x + (size_t)(n0 + l15) * HIDC;
    short8v a[4];
    for (int kt = 0; kt < 4; ++kt){
        const float4* p = (const float4*)(xr + kt * 32 + lhi * 8);
        float4 f0 = p[0], f1 = p[1];
        short8v tv;
        tv[0]=(short)f2bf(f0.x); tv[1]=(short)f2bf(f0.y); tv[2]=(short)f2bf(f0.z); tv[3]=(short)f2bf(f0.w);
        tv[4]=(short)f2bf(f1.x); tv[5]=(short)f2bf(f1.y); tv[6]=(short)f2bf(f1.z); tv[7]=(short)f2bf(f1.w);
        a[kt] = tv;
    }
    for (int ct = wv; ct < 8; ct += 4){
        const short8v* bp = ((const short8v*)wp) + ct * 256 + lane;
        f32x4 acc = {0.f, 0.f, 0.f, 0.f};
        acc = __builtin_amdgcn_mfma_f32_16x16x32_bf16(a[0], bp[0],   acc, 0, 0, 0);
        acc = __builtin_amdgcn_mfma_f32_16x16x32_bf16(a[1], bp[64],  acc, 0, 0, 0);
        acc = __builtin_amdgcn_mfma_f32_16x16x32_bf16(a[2], bp[128], acc, 0, 0, 0);
        acc = __builtin_amdgcn_mfma_f32_16x16x32_bf16(a[3], bp[192], acc, 0, 0, 0);
        int r0 = n0 + lhi * 4, col = ct * 16 + l15;
        float bb = lin_b[col];
        for (int r = 0; r < 4; ++r){
            float v = acc[r] + bb;
            hout[(size_t)(r0 + r) * HIDC + col] = v;
            hbf [(size_t)(r0 + r) * HIDC + col] = f2bf(v);
        }
    }
}

// [bases(bf16, cols 0..63) | wcoef(fp32 + comb_b, cols 64..159)] = hbf @ [bw|cw]
__global__ __launch_bounds__(256) void k_gemm_layer(const u16* hbf, const u16* wp,
                                                    const float* comb_b_l, u16* basesb, float* wcoef){
    int lane = threadIdx.x & 63, wv = threadIdx.x >> 6;
    int n0 = blockIdx.x * 16;
    int l15 = lane & 15, lhi = lane >> 4;
    const short8v* arow = (const short8v*)(hbf + (size_t)(n0 + l15) * HIDC);
    short8v a0 = arow[lhi], a1 = arow[4 + lhi], a2 = arow[8 + lhi], a3 = arow[12 + lhi];
    for (int ct = wv; ct < 10; ct += 4){
        const short8v* bp = ((const short8v*)wp) + ct * 256 + lane;
        f32x4 acc = {0.f, 0.f, 0.f, 0.f};
        acc = __builtin_amdgcn_mfma_f32_16x16x32_bf16(a0, bp[0],   acc, 0, 0, 0);
        acc = __builtin_amdgcn_mfma_f32_16x16x32_bf16(a1, bp[64],  acc, 0, 0, 0);
        acc = __builtin_amdgcn_mfma_f32_16x16x32_bf16(a2, bp[128], acc, 0, 0, 0);
        acc = __builtin_amdgcn_mfma_f32_16x16x32_bf16(a3, bp[192], acc, 0, 0, 0);
        int r0 = n0 + lhi * 4, col = ct * 16 + l15;
        if (ct < 4){
            for (int r = 0; r < 4; ++r)
                basesb[(size_t)(r0 + r) * 64 + col] = f2bf(acc[r]);
        } else {
            int c = col - 64;
            float bb = comb_b_l[c];
            for (int r = 0; r < 4; ++r)
                wcoef[(size_t)(r0 + r) * 96 + c] = acc[r] + bb;
        }
    }
}

// ---------------- edge aggregation: half-wave per node, CSR, no atomics --------
__global__ __launch_bounds__(256) void k_agg(const u16* basesb, const int* rowptr,
                                             const int* ssrc, float* agg){
    int tid = threadIdx.x;
    int lane = tid & 63, wv = tid >> 6;
    int n = (blockIdx.x * 4 + wv) * 2 + (lane >> 5);
    int sl = lane & 31;
    int rp0 = rowptr[n], rp1 = rowptr[n + 1];
    float s0 = 0.f, s1 = 0.f, m0 = -INFINITY, m1 = -INFINITY;
    for (int e = rp0; e < rp1; ++e){
        int s = ssrc[e];
        u32 u = *(const u32*)(basesb + (size_t)s * 64 + 2 * sl);
        float f0 = __uint_as_float((u & 0xffffu) << 16);
        float f1 = __uint_as_float(u & 0xffff0000u);
        s0 += f0; s1 += f1;
        m0 = fmaxf(m0, f0); m1 = fmaxf(m1, f1);
    }
    if (rp1 == rp0){ m0 = 0.f; m1 = 0.f; }
    float* ap = agg + (size_t)n * HIDC;
    *(float2*)(ap + 2 * sl)      = make_float2(s0, s1);
    *(float2*)(ap + 64 + 2 * sl) = make_float2(m0, m1);
}

// ---------------- combine (einsum) + per-graph stats ----------------
__global__ __launch_bounds__(256) void k_combine(const float* agg, const float* wcoef,
                                                 const int* deg, const int* batch,
                                                 const float* conv_b_l, float* gbuf,
                                                 float* gs1, float* gs2){
    int tid = threadIdx.x;
    int c = tid & 127, sub = tid >> 7;
    int f = c & 15, hh = c >> 4;
    int n0 = blockIdx.x * 8;
    float cb = conv_b_l[c];
    float accS = 0.f, accS2 = 0.f; int curG = -1;
    for (int i = 0; i < 4; ++i){
        int n = n0 + 2 * i + sub;
        const float* wr = wcoef + (size_t)n * 96 + hh * 12;
        float4 w0 = *(const float4*)(wr);
        float4 w1 = *(const float4*)(wr + 4);
        float4 w2 = *(const float4*)(wr + 8);
        const float* ap = agg + (size_t)n * HIDC;
        float inv = 1.0f / fmaxf((float)deg[n], 1.0f);
        float sA = ap[f],      sB = ap[16 + f], sC = ap[32 + f], sD = ap[48 + f];
        float xA = ap[64 + f], xB = ap[80 + f], xC = ap[96 + f], xD = ap[112 + f];
        float g = cb;
        g += w0.x * sA + w0.y * sB + w0.z * sC + w0.w * sD;
        g += (w1.x * sA + w1.y * sB + w1.z * sC + w1.w * sD) * inv;
        g += w2.x * xA + w2.y * xB + w2.z * xC + w2.w * xD;
        gbuf[(size_t)n * HIDC + c] = g;
        int bg = batch[n];
        if (bg != curG){
            if (curG >= 0){
                atomicAdd(&gs1[curG * HIDC + c], accS);
                atomicAdd(&gs2[curG * HIDC + c], accS2);
            }
            curG = bg; accS = 0.f; accS2 = 0.f;
        }
        accS += g; accS2 += g * g;
    }
    if (curG >= 0){
        atomicAdd(&gs1[curG * HIDC + c], accS);
        atomicAdd(&gs2[curG * HIDC + c], accS2);
    }
}

__global__ __launch_bounds__(256) void k_finalize(float* gs1, float* gs2, const int* npg,
                                                  const float* gn_ms_l, const float* gn_w_l,
                                                  float* meanms, float* winv){
    int idx = blockIdx.x * 256 + threadIdx.x;   // 8192
    int bg = idx >> 7, c = idx & 127;
    float cnt = fmaxf((float)npg[bg], 1.0f);
    float s1 = gs1[idx], s2 = gs2[idx];
    float mean = s1 / cnt, ex2 = s2 / cnt;
    float ms = gn_ms_l[c];
    float var = ex2 - mean * mean * ms * (2.0f - ms);
    float inv = rsqrtf(fmaxf(var, 0.f) + 1e-6f);
    meanms[idx] = mean * ms;
    winv[idx]   = gn_w_l[c] * inv;
    gs1[idx] = 0.f; gs2[idx] = 0.f;   // reset for next layer
}

// ---------------- norm + relu + residual (+ pooling on last layer) -------------
__global__ __launch_bounds__(256) void k_update(const float* gbuf, const int* batch,
                                                const float* meanms, const float* winv,
                                                const float* gn_b_l, float* hout, u16* hbf,
                                                float* ysum, int last){
    int tid = threadIdx.x;
    int c = tid & 127, sub = tid >> 7;
    int n0 = blockIdx.x * 8;
    float gb = gn_b_l[c];
    float accY = 0.f; int curG = -1;
    for (int i = 0; i < 4; ++i){
        int n = n0 + 2 * i + sub;
        int bg = batch[n];
        float g = gbuf[(size_t)n * HIDC + c];
        float val = (g - meanms[bg * HIDC + c]) * winv[bg * HIDC + c] + gb;
        val = fmaxf(val, 0.f);
        float hn = hout[(size_t)n * HIDC + c] + val;
        hout[(size_t)n * HIDC + c] = hn;
        hbf [(size_t)n * HIDC + c] = f2bf(hn);
        if (last){
            if (bg != curG){
                if (curG >= 0) atomicAdd(&ysum[curG * HIDC + c], accY);
                curG = bg; accY = 0.f;
            }
            accY += hn;
        }
    }
    if (last && curG >= 0) atomicAdd(&ysum[curG * HIDC + c], accY);
}

__global__ __launch_bounds__(256) void k_yscale(float* y, const int* npg){
    int idx = blockIdx.x * 256 + threadIdx.x;  // 8192
    int bg = idx >> 7;
    y[idx] /= fmaxf((float)npg[bg], 1.0f);
}

// ---------------- launch ----------------
extern "C" void kernel_launch(void* const* d_in, const int* in_sizes, int n_in,
                              void* d_out, int out_size, void* d_ws, size_t ws_size,
                              hipStream_t stream){
    const float* x       = (const float*)d_in[0];
    const int*   ei      = (const int*)d_in[1];
    const int*   batch   = (const int*)d_in[2];
    const int*   npg     = (const int*)d_in[3];
    const float* lin_w   = (const float*)d_in[4];
    const float* lin_b   = (const float*)d_in[5];
    const float* bases_w = (const float*)d_in[6];
    const float* comb_w  = (const float*)d_in[7];
    const float* comb_b  = (const float*)d_in[8];
    const float* conv_b  = (const float*)d_in[9];
    const float* gn_w    = (const float*)d_in[10];
    const float* gn_b    = (const float*)d_in[11];
    const float* gn_ms   = (const float*)d_in[12];
    (void)in_sizes; (void)n_in; (void)out_size; (void)ws_size;

    float* hout = (float*)d_out;
    float* yout = hout + (size_t)NN * HIDC;

    char* basep = (char*)d_ws;
    size_t o = 0;
    auto alloc = [&](size_t bytes) -> char* {
        char* p = basep + o;
        o = (o + bytes + 255) & ~(size_t)255;
        return p;
    };
    u16*   wpack  = (u16*)  alloc((size_t)98304 * 2);
    u16*   hbf    = (u16*)  alloc((size_t)NN * HIDC * 2);
    u16*   basesb = (u16*)  alloc((size_t)NN * 64 * 2);
    float* wcoef  = (float*)alloc((size_t)NN * 96 * 4);
    float* agg    = (float*)alloc((size_t)NN * HIDC * 4);
    float* gbuf   = (float*)alloc((size_t)NN * HIDC * 4);
    int*   deg    = (int*)  alloc((size_t)NN * 4);
    int*   rowptr = (int*)  alloc((size_t)(NN + 1) * 4);
    int*   fill   = (int*)  alloc((size_t)NN * 4);
    int*   ssrc   = (int*)  alloc((size_t)EE * 4);
    int*   bsums  = (int*)  alloc(128 * 4);
    int*   boffs  = (int*)  alloc(128 * 4);
    float* gs1    = (float*)alloc(8192 * 4);   // 32768B, 256-aligned ⇒ gs2 contiguous
    float* gs2    = (float*)alloc(8192 * 4);
    float* meanms = (float*)alloc(8192 * 4);
    float* winv   = (float*)alloc(8192 * 4);

    hipMemsetAsync(deg,  0, (size_t)NN * 4, stream);
    hipMemsetAsync(fill, 0, (size_t)NN * 4, stream);
    hipMemsetAsync(gs1,  0, (size_t)8192 * 4 * 2, stream);
    hipMemsetAsync(yout, 0, (size_t)8192 * 4, stream);

    k_pack   <<<384,  256, 0, stream>>>(lin_w, bases_w, comb_w, wpack);
    k_hist   <<<6250, 256, 0, stream>>>(ei + EE, deg);
    k_scan1  <<<98,   256, 0, stream>>>(deg, bsums);
    k_scan2  <<<1,    64,  0, stream>>>(bsums, boffs, 98);
    k_scan3  <<<98,   256, 0, stream>>>(deg, boffs, rowptr);
    k_scatter<<<6250, 256, 0, stream>>>(ei, ei + EE, rowptr, fill, ssrc);

    k_gemm_lin<<<6250, 256, 0, stream>>>(x, wpack, lin_b, hout, hbf);

    for (int l = 0; l < LL; ++l){
        k_gemm_layer<<<6250, 256, 0, stream>>>(hbf, wpack + 16384 + l * 20480,
                                               comb_b + l * 96, basesb, wcoef);
        k_agg     <<<12500, 256, 0, stream>>>(basesb, rowptr, ssrc, agg);
        k_combine <<<12500, 256, 0, stream>>>(agg, wcoef, deg, batch,
                                              conv_b + l * HIDC, gbuf, gs1, gs2);
        k_finalize<<<32,    256, 0, stream>>>(gs1, gs2, npg, gn_ms + l * HIDC,
                                              gn_w + l * HIDC, meanms, winv);
        k_update  <<<12500, 256, 0, stream>>>(gbuf, batch, meanms, winv,
                                              gn_b + l * HIDC, hout, hbf, yout, l == 3 ? 1 : 0);
    }
    k_yscale<<<32, 256, 0, stream>>>(yout, npg);
}

// Round 2
// 1035.627 us; speedup vs baseline: 1.1959x; 1.1959x over previous
//
#include <hip/hip_runtime.h>

#define NN   100000
#define EE   1600000
#define GG   64
#define HIDC 128
#define LL   4

typedef unsigned short u16;
typedef unsigned int   u32;
typedef __attribute__((ext_vector_type(8))) short short8v;
typedef __attribute__((ext_vector_type(4))) float f32x4;

__device__ __forceinline__ u16 f2bf(float f){
    u32 u = __float_as_uint(f);
    u32 r = (u + 0x7fffu + ((u >> 16) & 1u)) >> 16;
    return (u16)r;
}
__device__ __forceinline__ float bfl(u32 u){ return __uint_as_float((u & 0xffffu) << 16); }
__device__ __forceinline__ float bfh(u32 u){ return __uint_as_float(u & 0xffff0000u); }

// ---------------- weight packing: fp32 [K=128][M] -> bf16 MFMA B-frag order ----
// dst element within a matrix: ct*2048 + kt*512 + lane*8 + j
// holds W[k = kt*32 + (lane>>4)*8 + j][c = ct*16 + (lane&15)]
__global__ __launch_bounds__(256) void k_pack(const float* lin_w, const float* bases_w,
                                              const float* comb_w, u16* wpack){
    int t = blockIdx.x * 256 + threadIdx.x;
    if (t >= 98304) return;
    int li, m, isLin;
    if (t < 16384){ isLin = 1; li = 0; m = t; }
    else { isLin = 0; int u = t - 16384; li = u / 20480; m = u % 20480; }
    int j = m & 7, lane = (m >> 3) & 63, kt = (m >> 9) & 3, ct = m >> 11;
    int k = kt * 32 + ((lane >> 4) << 3) + j;
    int c = ct * 16 + (lane & 15);
    float v;
    if (isLin) v = lin_w[k * HIDC + c];
    else       v = (c < 64) ? bases_w[(li * HIDC + k) * 64 + c]
                            : comb_w[(li * HIDC + k) * 96 + (c - 64)];
    wpack[t] = f2bf(v);
}

// ---------------- CSR build ----------------
__global__ __launch_bounds__(256) void k_hist(const int* dst, int* deg){
    int e = blockIdx.x * 256 + threadIdx.x;
    if (e < EE) atomicAdd(&deg[dst[e]], 1);
}

__global__ __launch_bounds__(256) void k_scan1(const int* deg, int* bsums){
    __shared__ int sd[256];
    int b = blockIdx.x, t = threadIdx.x, base = b * 1024;
    int s = 0;
    for (int j = 0; j < 4; ++j){ int i = base + j * 256 + t; if (i < NN) s += deg[i]; }
    sd[t] = s; __syncthreads();
    for (int o = 128; o > 0; o >>= 1){ if (t < o) sd[t] += sd[t + o]; __syncthreads(); }
    if (t == 0) bsums[b] = sd[0];
}

__global__ void k_scan2(const int* bsums, int* boffs, int nb){
    if (threadIdx.x == 0 && blockIdx.x == 0){
        int run = 0;
        for (int b = 0; b < nb; ++b){ boffs[b] = run; run += bsums[b]; }
    }
}

__global__ __launch_bounds__(256) void k_scan3(const int* deg, const int* boffs, int* rowptr){
    __shared__ int ss[256];
    int b = blockIdx.x, t = threadIdx.x, base = b * 1024;
    int v[4]; int s = 0;
    for (int j = 0; j < 4; ++j){ int i = base + t * 4 + j; v[j] = (i < NN) ? deg[i] : 0; s += v[j]; }
    ss[t] = s; __syncthreads();
    for (int o = 1; o < 256; o <<= 1){
        int val = 0; if (t >= o) val = ss[t - o];
        __syncthreads(); ss[t] += val; __syncthreads();
    }
    int run = boffs[b] + (ss[t] - s);
    for (int j = 0; j < 4; ++j){ int i = base + t * 4 + j; if (i < NN) rowptr[i] = run; run += v[j]; }
    if (b == 0 && t == 0) rowptr[NN] = EE;
}

__global__ __launch_bounds__(256) void k_scatter(const int* src, const int* dst,
                                                 const int* rowptr, int* fill, int* ssrc){
    int e = blockIdx.x * 256 + threadIdx.x;
    if (e < EE){
        int d = dst[e];
        int pos = rowptr[d] + atomicAdd(&fill[d], 1);
        ssrc[pos] = src[e];
    }
}

// ------------- fused: lin GEMM (x @ lin_w + b) -> hout fp32 + layer-0 GEMM -----
__global__ __launch_bounds__(256) void k_lin_gemm0(const float* x, const u16* wpack,
                                                   const float* lin_b, const float* comb_b0,
                                                   float* hout, u16* basesb, float* wcoef){
    __shared__ u16 lA[16 * 136];   // padded row stride 272B
    int tid = threadIdx.x;
    int lane = tid & 63, wv = tid >> 6;
    int n0 = blockIdx.x * 16;
    int l15 = lane & 15, lhi = lane >> 4;

    // phase 1: h = x @ lin_w + lin_b
    const float* xr = x + (size_t)(n0 + l15) * HIDC;
    short8v a[4];
    for (int kt = 0; kt < 4; ++kt){
        const float4* p = (const float4*)(xr + kt * 32 + lhi * 8);
        float4 f0 = p[0], f1 = p[1];
        short8v tv;
        tv[0]=(short)f2bf(f0.x); tv[1]=(short)f2bf(f0.y); tv[2]=(short)f2bf(f0.z); tv[3]=(short)f2bf(f0.w);
        tv[4]=(short)f2bf(f1.x); tv[5]=(short)f2bf(f1.y); tv[6]=(short)f2bf(f1.z); tv[7]=(short)f2bf(f1.w);
        a[kt] = tv;
    }
    const u16* wlin = wpack;
    for (int ct = wv; ct < 8; ct += 4){
        const short8v* bp = ((const short8v*)wlin) + ct * 256 + lane;
        f32x4 acc = {0.f, 0.f, 0.f, 0.f};
        acc = __builtin_amdgcn_mfma_f32_16x16x32_bf16(a[0], bp[0],   acc, 0, 0, 0);
        acc = __builtin_amdgcn_mfma_f32_16x16x32_bf16(a[1], bp[64],  acc, 0, 0, 0);
        acc = __builtin_amdgcn_mfma_f32_16x16x32_bf16(a[2], bp[128], acc, 0, 0, 0);
        acc = __builtin_amdgcn_mfma_f32_16x16x32_bf16(a[3], bp[192], acc, 0, 0, 0);
        int rl0 = lhi * 4, col = ct * 16 + l15;
        float bb = lin_b[col];
        for (int r = 0; r < 4; ++r){
            float v = acc[r] + bb;
            hout[(size_t)(n0 + rl0 + r) * HIDC + col] = v;
            lA[(rl0 + r) * 136 + col] = f2bf(v);
        }
    }
    __syncthreads();

    // phase 2: [bases | wcoef] = h_bf16 @ [bw0 | cw0]
    const u16* ar = lA + l15 * 136;
    short8v b0 = *(const short8v*)(ar + lhi * 8);
    short8v b1 = *(const short8v*)(ar + 32 + lhi * 8);
    short8v b2 = *(const short8v*)(ar + 64 + lhi * 8);
    short8v b3 = *(const short8v*)(ar + 96 + lhi * 8);
    const u16* wl = wpack + 16384;
    for (int ct = wv; ct < 10; ct += 4){
        const short8v* bp = ((const short8v*)wl) + ct * 256 + lane;
        f32x4 acc = {0.f, 0.f, 0.f, 0.f};
        acc = __builtin_amdgcn_mfma_f32_16x16x32_bf16(b0, bp[0],   acc, 0, 0, 0);
        acc = __builtin_amdgcn_mfma_f32_16x16x32_bf16(b1, bp[64],  acc, 0, 0, 0);
        acc = __builtin_amdgcn_mfma_f32_16x16x32_bf16(b2, bp[128], acc, 0, 0, 0);
        acc = __builtin_amdgcn_mfma_f32_16x16x32_bf16(b3, bp[192], acc, 0, 0, 0);
        int r0 = n0 + lhi * 4, col = ct * 16 + l15;
        if (ct < 4){
            for (int r = 0; r < 4; ++r)
                basesb[(size_t)(r0 + r) * 64 + col] = f2bf(acc[r]);
        } else {
            int c = col - 64;
            float bb = comb_b0[c];
            for (int r = 0; r < 4; ++r)
                wcoef[(size_t)(r0 + r) * 96 + c] = acc[r] + bb;
        }
    }
}

// ------------- fused: edge aggregation + combine einsum + graph stats ----------
__global__ __launch_bounds__(256) void k_aggcmb(const u16* basesb, const int* rowptr,
                                                const int* ssrc, const float* wcoef,
                                                const int* batch, const float* conv_b_l,
                                                float* gbuf, float* gs1, float* gs2){
    __shared__ float sAgg[8 * 128];
    __shared__ float sInv[8];
    int tid = threadIdx.x;

    // phase 1: gather-aggregate, half-wave (32 lanes) per node, 8 nodes/block
    {
        int wv = tid >> 6, half = (tid >> 5) & 1, sl = tid & 31;
        int nb = wv * 2 + half;
        int n = blockIdx.x * 8 + nb;
        int rp0 = rowptr[n], rp1 = rowptr[n + 1];
        float s0 = 0.f, s1 = 0.f, m0 = -INFINITY, m1 = -INFINITY;
        int e = rp0;
        for (; e + 4 <= rp1; e += 4){
            int ia = ssrc[e], ib = ssrc[e+1], ic = ssrc[e+2], id = ssrc[e+3];
            u32 ua = *(const u32*)(basesb + (size_t)ia * 64 + 2 * sl);
            u32 ub = *(const u32*)(basesb + (size_t)ib * 64 + 2 * sl);
            u32 uc = *(const u32*)(basesb + (size_t)ic * 64 + 2 * sl);
            u32 ud = *(const u32*)(basesb + (size_t)id * 64 + 2 * sl);
            float a0 = bfl(ua), a1 = bfh(ua), b0 = bfl(ub), b1 = bfh(ub);
            float c0 = bfl(uc), c1 = bfh(uc), d0 = bfl(ud), d1 = bfh(ud);
            s0 += (a0 + b0) + (c0 + d0);
            s1 += (a1 + b1) + (c1 + d1);
            m0 = fmaxf(fmaxf(m0, a0), fmaxf(b0, fmaxf(c0, d0)));
            m1 = fmaxf(fmaxf(m1, a1), fmaxf(b1, fmaxf(c1, d1)));
        }
        for (; e < rp1; ++e){
            int s = ssrc[e];
            u32 u = *(const u32*)(basesb + (size_t)s * 64 + 2 * sl);
            float f0 = bfl(u), f1 = bfh(u);
            s0 += f0; s1 += f1;
            m0 = fmaxf(m0, f0); m1 = fmaxf(m1, f1);
        }
        if (rp1 == rp0){ m0 = 0.f; m1 = 0.f; }
        float* ap = sAgg + nb * 128;
        *(float2*)(ap + 2 * sl)      = make_float2(s0, s1);
        *(float2*)(ap + 64 + 2 * sl) = make_float2(m0, m1);
        if (sl == 0) sInv[nb] = 1.0f / fmaxf((float)(rp1 - rp0), 1.0f);
    }
    __syncthreads();

    // phase 2: g = einsum(w, [sum; mean; max]) + conv_b, plus per-graph stats
    {
        int c = tid & 127, half2 = tid >> 7;
        int f = c & 15, hh = c >> 4;
        float cb = conv_b_l[c];
        float accS = 0.f, accS2 = 0.f; int curG = -1;
        for (int i = 0; i < 4; ++i){
            int nb = i * 2 + half2;
            int n = blockIdx.x * 8 + nb;
            const float* wr = wcoef + (size_t)n * 96 + hh * 12;
            float4 w0 = *(const float4*)(wr);
            float4 w1 = *(const float4*)(wr + 4);
            float4 w2 = *(const float4*)(wr + 8);
            const float* ap = sAgg + nb * 128;
            float inv = sInv[nb];
            float sA = ap[f],      sB = ap[16 + f], sC = ap[32 + f], sD = ap[48 + f];
            float xA = ap[64 + f], xB = ap[80 + f], xC = ap[96 + f], xD = ap[112 + f];
            float g = cb;
            g += w0.x * sA + w0.y * sB + w0.z * sC + w0.w * sD;
            g += (w1.x * sA + w1.y * sB + w1.z * sC + w1.w * sD) * inv;
            g += w2.x * xA + w2.y * xB + w2.z * xC + w2.w * xD;
            gbuf[(size_t)n * HIDC + c] = g;
            int bg = batch[n];
            if (bg != curG){
                if (curG >= 0){
                    atomicAdd(&gs1[curG * HIDC + c], accS);
                    atomicAdd(&gs2[curG * HIDC + c], accS2);
                }
                curG = bg; accS = 0.f; accS2 = 0.f;
            }
            accS += g; accS2 += g * g;
        }
        if (curG >= 0){
            atomicAdd(&gs1[curG * HIDC + c], accS);
            atomicAdd(&gs2[curG * HIDC + c], accS2);
        }
    }
}

__global__ __launch_bounds__(256) void k_finalize(float* gs1, float* gs2, const int* npg,
                                                  const float* gn_ms_l, const float* gn_w_l,
                                                  float* meanms, float* winv){
    int idx = blockIdx.x * 256 + threadIdx.x;   // 8192
    int bg = idx >> 7, c = idx & 127;
    float cnt = fmaxf((float)npg[bg], 1.0f);
    float s1 = gs1[idx], s2 = gs2[idx];
    float mean = s1 / cnt, ex2 = s2 / cnt;
    float ms = gn_ms_l[c];
    float var = ex2 - mean * mean * ms * (2.0f - ms);
    float inv = rsqrtf(fmaxf(var, 0.f) + 1e-6f);
    meanms[idx] = mean * ms;
    winv[idx]   = gn_w_l[c] * inv;
    gs1[idx] = 0.f; gs2[idx] = 0.f;   // reset for next layer
}

// ------------- fused: norm+relu+residual -> h, then next-layer GEMM ------------
__global__ __launch_bounds__(256) void k_upgemm(const float* gbuf, const int* batch,
                                                const float* meanms, const float* winv,
                                                const float* gn_b_l, float* hout,
                                                const u16* wp_next, const float* comb_b_next,
                                                u16* basesb, float* wcoef){
    __shared__ u16 lA[16 * 136];   // 16 rows x 128 bf16, padded stride 272B
    int tid = threadIdx.x;
    int n0 = blockIdx.x * 16;

    // phase 1: update 16 nodes x 128 channels
    {
        int c = tid & 127, half = tid >> 7;
        float gb = gn_b_l[c];
        for (int i = 0; i < 8; ++i){
            int r = i * 2 + half;
            int n = n0 + r;
            int bg = batch[n];
            float g = gbuf[(size_t)n * HIDC + c];
            float val = fmaxf((g - meanms[bg * HIDC + c]) * winv[bg * HIDC + c] + gb, 0.f);
            float hn = hout[(size_t)n * HIDC + c] + val;
            hout[(size_t)n * HIDC + c] = hn;
            lA[r * 136 + c] = f2bf(hn);
        }
    }
    __syncthreads();

    // phase 2: [bases | wcoef] = h_bf16 @ [bw | cw] for next layer
    int lane = tid & 63, wv = tid >> 6;
    int l15 = lane & 15, lhi = lane >> 4;
    const u16* ar = lA + l15 * 136;
    short8v b0 = *(const short8v*)(ar + lhi * 8);
    short8v b1 = *(const short8v*)(ar + 32 + lhi * 8);
    short8v b2 = *(const short8v*)(ar + 64 + lhi * 8);
    short8v b3 = *(const short8v*)(ar + 96 + lhi * 8);
    for (int ct = wv; ct < 10; ct += 4){
        const short8v* bp = ((const short8v*)wp_next) + ct * 256 + lane;
        f32x4 acc = {0.f, 0.f, 0.f, 0.f};
        acc = __builtin_amdgcn_mfma_f32_16x16x32_bf16(b0, bp[0],   acc, 0, 0, 0);
        acc = __builtin_amdgcn_mfma_f32_16x16x32_bf16(b1, bp[64],  acc, 0, 0, 0);
        acc = __builtin_amdgcn_mfma_f32_16x16x32_bf16(b2, bp[128], acc, 0, 0, 0);
        acc = __builtin_amdgcn_mfma_f32_16x16x32_bf16(b3, bp[192], acc, 0, 0, 0);
        int r0 = n0 + lhi * 4, col = ct * 16 + l15;
        if (ct < 4){
            for (int r = 0; r < 4; ++r)
                basesb[(size_t)(r0 + r) * 64 + col] = f2bf(acc[r]);
        } else {
            int c = col - 64;
            float bb = comb_b_next[c];
            for (int r = 0; r < 4; ++r)
                wcoef[(size_t)(r0 + r) * 96 + c] = acc[r] + bb;
        }
    }
}

// ------------- last layer: norm+relu+residual + mean-pool accumulation ---------
__global__ __launch_bounds__(256) void k_uplast(const float* gbuf, const int* batch,
                                                const float* meanms, const float* winv,
                                                const float* gn_b_l, float* hout, float* ysum){
    int tid = threadIdx.x;
    int c = tid & 127, half = tid >> 7;
    int n0 = blockIdx.x * 8;
    float gb = gn_b_l[c];
    float accY = 0.f; int curG = -1;
    for (int i = 0; i < 4; ++i){
        int n = n0 + i * 2 + half;
        int bg = batch[n];
        float g = gbuf[(size_t)n * HIDC + c];
        float val = fmaxf((g - meanms[bg * HIDC + c]) * winv[bg * HIDC + c] + gb, 0.f);
        float hn = hout[(size_t)n * HIDC + c] + val;
        hout[(size_t)n * HIDC + c] = hn;
        if (bg != curG){
            if (curG >= 0) atomicAdd(&ysum[curG * HIDC + c], accY);
            curG = bg; accY = 0.f;
        }
        accY += hn;
    }
    if (curG >= 0) atomicAdd(&ysum[curG * HIDC + c], accY);
}

__global__ __launch_bounds__(256) void k_yscale(float* y, const int* npg){
    int idx = blockIdx.x * 256 + threadIdx.x;  // 8192
    int bg = idx >> 7;
    y[idx] /= fmaxf((float)npg[bg], 1.0f);
}

// ---------------- launch ----------------
extern "C" void kernel_launch(void* const* d_in, const int* in_sizes, int n_in,
                              void* d_out, int out_size, void* d_ws, size_t ws_size,
                              hipStream_t stream){
    const float* x       = (const float*)d_in[0];
    const int*   ei      = (const int*)d_in[1];
    const int*   batch   = (const int*)d_in[2];
    const int*   npg     = (const int*)d_in[3];
    const float* lin_w   = (const float*)d_in[4];
    const float* lin_b   = (const float*)d_in[5];
    const float* bases_w = (const float*)d_in[6];
    const float* comb_w  = (const float*)d_in[7];
    const float* comb_b  = (const float*)d_in[8];
    const float* conv_b  = (const float*)d_in[9];
    const float* gn_w    = (const float*)d_in[10];
    const float* gn_b    = (const float*)d_in[11];
    const float* gn_ms   = (const float*)d_in[12];
    (void)in_sizes; (void)n_in; (void)out_size; (void)ws_size;

    float* hout = (float*)d_out;
    float* yout = hout + (size_t)NN * HIDC;

    char* basep = (char*)d_ws;
    size_t o = 0;
    auto alloc = [&](size_t bytes) -> char* {
        char* p = basep + o;
        o = (o + bytes + 255) & ~(size_t)255;
        return p;
    };
    u16*   wpack  = (u16*)  alloc((size_t)98304 * 2);
    u16*   basesb = (u16*)  alloc((size_t)NN * 64 * 2);
    float* wcoef  = (float*)alloc((size_t)NN * 96 * 4);
    float* gbuf   = (float*)alloc((size_t)NN * HIDC * 4);
    int*   deg    = (int*)  alloc((size_t)NN * 4);
    int*   rowptr = (int*)  alloc((size_t)(NN + 1) * 4);
    int*   fill   = (int*)  alloc((size_t)NN * 4);
    int*   ssrc   = (int*)  alloc((size_t)EE * 4);
    int*   bsums  = (int*)  alloc(128 * 4);
    int*   boffs  = (int*)  alloc(128 * 4);
    float* gs1    = (float*)alloc(8192 * 4);
    float* gs2    = (float*)alloc(8192 * 4);
    float* meanms = (float*)alloc(8192 * 4);
    float* winv   = (float*)alloc(8192 * 4);

    hipMemsetAsync(deg,  0, (size_t)NN * 4, stream);
    hipMemsetAsync(fill, 0, (size_t)NN * 4, stream);
    hipMemsetAsync(gs1,  0, (size_t)8192 * 4, stream);
    hipMemsetAsync(gs2,  0, (size_t)8192 * 4, stream);
    hipMemsetAsync(yout, 0, (size_t)8192 * 4, stream);

    k_pack   <<<384,  256, 0, stream>>>(lin_w, bases_w, comb_w, wpack);
    k_hist   <<<6250, 256, 0, stream>>>(ei + EE, deg);
    k_scan1  <<<98,   256, 0, stream>>>(deg, bsums);
    k_scan2  <<<1,    64,  0, stream>>>(bsums, boffs, 98);
    k_scan3  <<<98,   256, 0, stream>>>(deg, boffs, rowptr);
    k_scatter<<<6250, 256, 0, stream>>>(ei, ei + EE, rowptr, fill, ssrc);

    k_lin_gemm0<<<6250, 256, 0, stream>>>(x, wpack, lin_b, comb_b, hout, basesb, wcoef);

    for (int l = 0; l < LL; ++l){
        k_aggcmb  <<<12500, 256, 0, stream>>>(basesb, rowptr, ssrc, wcoef, batch,
                                              conv_b + l * HIDC, gbuf, gs1, gs2);
        k_finalize<<<32,    256, 0, stream>>>(gs1, gs2, npg, gn_ms + l * HIDC,
                                              gn_w + l * HIDC, meanms, winv);
        if (l < 3){
            k_upgemm<<<6250, 256, 0, stream>>>(gbuf, batch, meanms, winv,
                                               gn_b + l * HIDC, hout,
                                               wpack + 16384 + (l + 1) * 20480,
                                               comb_b + (l + 1) * 96, basesb, wcoef);
        } else {
            k_uplast<<<12500, 256, 0, stream>>>(gbuf, batch, meanms, winv,
                                                gn_b + l * HIDC, hout, yout);
        }
    }
    k_yscale<<<32, 256, 0, stream>>>(yout, npg);
}

// Round 4
// 988.490 us; speedup vs baseline: 1.2529x; 1.0477x over previous
//
#include <hip/hip_runtime.h>

#define NN   100000
#define EE   1600000
#define GG   64
#define HIDC 128
#define LL   4

typedef unsigned short u16;
typedef unsigned int   u32;
typedef __attribute__((ext_vector_type(8))) short short8v;
typedef __attribute__((ext_vector_type(4))) float f32x4;

__device__ __forceinline__ u16 f2bf(float f){
    u32 u = __float_as_uint(f);
    u32 r = (u + 0x7fffu + ((u >> 16) & 1u)) >> 16;
    return (u16)r;
}
__device__ __forceinline__ float bfl(u32 u){ return __uint_as_float(u << 16); }
__device__ __forceinline__ float bfh(u32 u){ return __uint_as_float(u & 0xffff0000u); }
__device__ __forceinline__ float bf1(u16 u){ return __uint_as_float(((u32)u) << 16); }

// ---------------- weight packing: fp32 [K=128][M] -> bf16 MFMA B-frag order ----
__global__ __launch_bounds__(256) void k_pack(const float* lin_w, const float* bases_w,
                                              const float* comb_w, u16* wpack){
    int t = blockIdx.x * 256 + threadIdx.x;
    if (t >= 98304) return;
    int li, m, isLin;
    if (t < 16384){ isLin = 1; li = 0; m = t; }
    else { isLin = 0; int u = t - 16384; li = u / 20480; m = u % 20480; }
    int j = m & 7, lane = (m >> 3) & 63, kt = (m >> 9) & 3, ct = m >> 11;
    int k = kt * 32 + ((lane >> 4) << 3) + j;
    int c = ct * 16 + (lane & 15);
    float v;
    if (isLin) v = lin_w[k * HIDC + c];
    else       v = (c < 64) ? bases_w[(li * HIDC + k) * 64 + c]
                            : comb_w[(li * HIDC + k) * 96 + (c - 64)];
    wpack[t] = f2bf(v);
}

// ---------------- CSR build ----------------
__global__ __launch_bounds__(256) void k_hist(const int* dst, int* deg){
    int e = blockIdx.x * 256 + threadIdx.x;
    if (e < EE) atomicAdd(&deg[dst[e]], 1);
}

__global__ __launch_bounds__(256) void k_scan1(const int* deg, int* bsums){
    __shared__ int sd[256];
    int b = blockIdx.x, t = threadIdx.x, base = b * 1024;
    int s = 0;
    for (int j = 0; j < 4; ++j){ int i = base + j * 256 + t; if (i < NN) s += deg[i]; }
    sd[t] = s; __syncthreads();
    for (int o = 128; o > 0; o >>= 1){ if (t < o) sd[t] += sd[t + o]; __syncthreads(); }
    if (t == 0) bsums[b] = sd[0];
}

__global__ void k_scan2(const int* bsums, int* boffs, int nb){
    if (threadIdx.x == 0 && blockIdx.x == 0){
        int run = 0;
        for (int b = 0; b < nb; ++b){ boffs[b] = run; run += bsums[b]; }
    }
}

__global__ __launch_bounds__(256) void k_scan3(const int* deg, const int* boffs, int* rowptr){
    __shared__ int ss[256];
    int b = blockIdx.x, t = threadIdx.x, base = b * 1024;
    int v[4]; int s = 0;
    for (int j = 0; j < 4; ++j){ int i = base + t * 4 + j; v[j] = (i < NN) ? deg[i] : 0; s += v[j]; }
    ss[t] = s; __syncthreads();
    for (int o = 1; o < 256; o <<= 1){
        int val = 0; if (t >= o) val = ss[t - o];
        __syncthreads(); ss[t] += val; __syncthreads();
    }
    int run = boffs[b] + (ss[t] - s);
    for (int j = 0; j < 4; ++j){ int i = base + t * 4 + j; if (i < NN) rowptr[i] = run; run += v[j]; }
    if (b == 0 && t == 0) rowptr[NN] = EE;
}

__global__ __launch_bounds__(256) void k_scatter(const int* src, const int* dst,
                                                 const int* rowptr, int* fill, int* ssrc){
    int e = blockIdx.x * 256 + threadIdx.x;
    if (e < EE){
        int d = dst[e];
        int pos = rowptr[d] + atomicAdd(&fill[d], 1);
        ssrc[pos] = src[e];
    }
}

// ------------- fused: lin GEMM (x @ lin_w + b) -> hout fp32 + layer-0 GEMM -----
__global__ __launch_bounds__(256) void k_lin_gemm0(const float* x, const u16* wpack,
                                                   const float* lin_b, const float* comb_b0,
                                                   float* hout, u16* basesb, u16* wcoefb){
    __shared__ u16 lA[16 * 136];
    int tid = threadIdx.x;
    int lane = tid & 63, wv = tid >> 6;
    int n0 = blockIdx.x * 16;
    int l15 = lane & 15, lhi = lane >> 4;

    const float* xr = x + (size_t)(n0 + l15) * HIDC;
    short8v a[4];
    for (int kt = 0; kt < 4; ++kt){
        const float4* p = (const float4*)(xr + kt * 32 + lhi * 8);
        float4 f0 = p[0], f1 = p[1];
        short8v tv;
        tv[0]=(short)f2bf(f0.x); tv[1]=(short)f2bf(f0.y); tv[2]=(short)f2bf(f0.z); tv[3]=(short)f2bf(f0.w);
        tv[4]=(short)f2bf(f1.x); tv[5]=(short)f2bf(f1.y); tv[6]=(short)f2bf(f1.z); tv[7]=(short)f2bf(f1.w);
        a[kt] = tv;
    }
    for (int ct = wv; ct < 8; ct += 4){
        const short8v* bp = ((const short8v*)wpack) + ct * 256 + lane;
        f32x4 acc = {0.f, 0.f, 0.f, 0.f};
        acc = __builtin_amdgcn_mfma_f32_16x16x32_bf16(a[0], bp[0],   acc, 0, 0, 0);
        acc = __builtin_amdgcn_mfma_f32_16x16x32_bf16(a[1], bp[64],  acc, 0, 0, 0);
        acc = __builtin_amdgcn_mfma_f32_16x16x32_bf16(a[2], bp[128], acc, 0, 0, 0);
        acc = __builtin_amdgcn_mfma_f32_16x16x32_bf16(a[3], bp[192], acc, 0, 0, 0);
        int rl0 = lhi * 4, col = ct * 16 + l15;
        float bb = lin_b[col];
        for (int r = 0; r < 4; ++r){
            float v = acc[r] + bb;
            hout[(size_t)(n0 + rl0 + r) * HIDC + col] = v;
            lA[(rl0 + r) * 136 + col] = f2bf(v);
        }
    }
    __syncthreads();

    const u16* ar = lA + l15 * 136;
    short8v b0 = *(const short8v*)(ar + lhi * 8);
    short8v b1 = *(const short8v*)(ar + 32 + lhi * 8);
    short8v b2 = *(const short8v*)(ar + 64 + lhi * 8);
    short8v b3 = *(const short8v*)(ar + 96 + lhi * 8);
    const u16* wl = wpack + 16384;
    for (int ct = wv; ct < 10; ct += 4){
        const short8v* bp = ((const short8v*)wl) + ct * 256 + lane;
        f32x4 acc = {0.f, 0.f, 0.f, 0.f};
        acc = __builtin_amdgcn_mfma_f32_16x16x32_bf16(b0, bp[0],   acc, 0, 0, 0);
        acc = __builtin_amdgcn_mfma_f32_16x16x32_bf16(b1, bp[64],  acc, 0, 0, 0);
        acc = __builtin_amdgcn_mfma_f32_16x16x32_bf16(b2, bp[128], acc, 0, 0, 0);
        acc = __builtin_amdgcn_mfma_f32_16x16x32_bf16(b3, bp[192], acc, 0, 0, 0);
        int r0 = n0 + lhi * 4, col = ct * 16 + l15;
        if (ct < 4){
            for (int r = 0; r < 4; ++r)
                basesb[(size_t)(r0 + r) * 64 + col] = f2bf(acc[r]);
        } else {
            int c = col - 64;
            float bb = comb_b0[c];
            for (int r = 0; r < 4; ++r)
                wcoefb[(size_t)(r0 + r) * 96 + c] = f2bf(acc[r] + bb);
        }
    }
}

// ------------- fused: edge aggregation (1 node/wave) + combine einsum ----------
__global__ __launch_bounds__(256) void k_aggcmb(const u16* __restrict__ basesb,
                                                const int* __restrict__ rowptr,
                                                const int* __restrict__ ssrc,
                                                const u16* __restrict__ wcoefb,
                                                const float* __restrict__ conv_b_l,
                                                u16* __restrict__ gbufb){
    __shared__ float sAgg[4 * 128];
    __shared__ float sInv[4];
    int tid = threadIdx.x;
    int wv = tid >> 6, lane = tid & 63;
    int half = lane >> 5, sl = lane & 31;
    int n = blockIdx.x * 4 + wv;
    int rp0 = rowptr[n], rp1 = rowptr[n + 1];
    float s0 = 0.f, s1 = 0.f, m0 = -INFINITY, m1 = -INFINITY;

    int e0 = rp0;
    // main loop: full 8-edge chunks, branch-free, 4 gathers in flight per wave
    for (; e0 + 8 <= rp1; e0 += 8){
        int ia = ssrc[e0 + half];
        int ib = ssrc[e0 + 2 + half];
        int ic = ssrc[e0 + 4 + half];
        int id = ssrc[e0 + 6 + half];
        u32 ua = *(const u32*)(basesb + ((size_t)ia << 6) + 2 * sl);
        u32 ub = *(const u32*)(basesb + ((size_t)ib << 6) + 2 * sl);
        u32 uc = *(const u32*)(basesb + ((size_t)ic << 6) + 2 * sl);
        u32 ud = *(const u32*)(basesb + ((size_t)id << 6) + 2 * sl);
        float a0 = bfl(ua), a1 = bfh(ua), b0 = bfl(ub), b1 = bfh(ub);
        float c0 = bfl(uc), c1 = bfh(uc), d0 = bfl(ud), d1 = bfh(ud);
        s0 += (a0 + b0) + (c0 + d0);
        s1 += (a1 + b1) + (c1 + d1);
        m0 = fmaxf(fmaxf(m0, a0), fmaxf(b0, fmaxf(c0, d0)));
        m1 = fmaxf(fmaxf(m1, a1), fmaxf(b1, fmaxf(c1, d1)));
    }
    // tail: up to 7 edges, predicated
    {
        int r = rp1 - e0;
        if (r > 0){
            bool va = half < r, vb = 2 + half < r, vc = 4 + half < r, vd = 6 + half < r;
            u32 ua = 0u, ub = 0u, uc = 0u, ud = 0u;
            if (va){ int i = ssrc[e0 + half];     ua = *(const u32*)(basesb + ((size_t)i << 6) + 2 * sl); }
            if (vb){ int i = ssrc[e0 + 2 + half]; ub = *(const u32*)(basesb + ((size_t)i << 6) + 2 * sl); }
            if (vc){ int i = ssrc[e0 + 4 + half]; uc = *(const u32*)(basesb + ((size_t)i << 6) + 2 * sl); }
            if (vd){ int i = ssrc[e0 + 6 + half]; ud = *(const u32*)(basesb + ((size_t)i << 6) + 2 * sl); }
            float a0 = bfl(ua), a1 = bfh(ua), b0 = bfl(ub), b1 = bfh(ub);
            float c0 = bfl(uc), c1 = bfh(uc), d0 = bfl(ud), d1 = bfh(ud);
            s0 += (a0 + b0) + (c0 + d0);
            s1 += (a1 + b1) + (c1 + d1);
            m0 = fmaxf(fmaxf(m0, va ? a0 : -INFINITY), fmaxf(vb ? b0 : -INFINITY,
                 fmaxf(vc ? c0 : -INFINITY, vd ? d0 : -INFINITY)));
            m1 = fmaxf(fmaxf(m1, va ? a1 : -INFINITY), fmaxf(vb ? b1 : -INFINITY,
                 fmaxf(vc ? c1 : -INFINITY, vd ? d1 : -INFINITY)));
        }
    }
    // merge the two half-waves (edges were interleaved even/odd)
    s0 += __shfl_xor(s0, 32); s1 += __shfl_xor(s1, 32);
    m0 = fmaxf(m0, __shfl_xor(m0, 32));
    m1 = fmaxf(m1, __shfl_xor(m1, 32));
    int degn = rp1 - rp0;
    if (degn == 0){ m0 = 0.f; m1 = 0.f; }
    if (half == 0){
        float* ap = sAgg + wv * 128;
        *(float2*)(ap + 2 * sl)      = make_float2(s0, s1);
        *(float2*)(ap + 64 + 2 * sl) = make_float2(m0, m1);
        if (sl == 0) sInv[wv] = 1.0f / fmaxf((float)degn, 1.0f);
    }
    __syncthreads();

    // phase 2: g = einsum(w, [sum; mean; max]) + conv_b  -> gbuf (bf16)
    int c = tid & 127, sub = tid >> 7;
    int f = c & 15, hh = c >> 4;
    float cb = conv_b_l[c];
    for (int i = 0; i < 2; ++i){
        int nb = i * 2 + sub;
        int n2 = blockIdx.x * 4 + nb;
        const u32* wu = (const u32*)(wcoefb + (size_t)n2 * 96 + hh * 12);
        u32 q0 = wu[0], q1 = wu[1], q2 = wu[2], q3 = wu[3], q4 = wu[4], q5 = wu[5];
        const float* ap = sAgg + nb * 128;
        float inv = sInv[nb];
        float sA = ap[f],      sB = ap[16 + f], sC = ap[32 + f], sD = ap[48 + f];
        float xA = ap[64 + f], xB = ap[80 + f], xC = ap[96 + f], xD = ap[112 + f];
        float g = cb;
        g += bfl(q0) * sA + bfh(q0) * sB + bfl(q1) * sC + bfh(q1) * sD;
        g += (bfl(q2) * sA + bfh(q2) * sB + bfl(q3) * sC + bfh(q3) * sD) * inv;
        g += bfl(q4) * xA + bfh(q4) * xB + bfl(q5) * xC + bfh(q5) * xD;
        gbufb[(size_t)n2 * HIDC + c] = f2bf(g);
    }
}

// ------------- per-graph stats from gbuf (bf16): few atomics ------------------
__global__ __launch_bounds__(256) void k_stats(const u16* __restrict__ gbufb,
                                               const int* __restrict__ batch,
                                               float* gs1, float* gs2){
    int tid = threadIdx.x;
    int c = tid & 127, sub = tid >> 7;
    int n0 = blockIdx.x * 500;
    float accS = 0.f, accS2 = 0.f; int curG = -1;
    for (int i = 0; i < 250; ++i){
        int n = n0 + i * 2 + sub;
        float g = bf1(gbufb[(size_t)n * HIDC + c]);
        int bg = batch[n];
        if (bg != curG){
            if (curG >= 0){
                atomicAdd(&gs1[curG * HIDC + c], accS);
                atomicAdd(&gs2[curG * HIDC + c], accS2);
            }
            curG = bg; accS = 0.f; accS2 = 0.f;
        }
        accS += g; accS2 += g * g;
    }
    if (curG >= 0){
        atomicAdd(&gs1[curG * HIDC + c], accS);
        atomicAdd(&gs2[curG * HIDC + c], accS2);
    }
}

__global__ __launch_bounds__(256) void k_finalize(float* gs1, float* gs2, const int* npg,
                                                  const float* gn_ms_l, const float* gn_w_l,
                                                  float* meanms, float* winv){
    int idx = blockIdx.x * 256 + threadIdx.x;   // 8192
    int bg = idx >> 7, c = idx & 127;
    float cnt = fmaxf((float)npg[bg], 1.0f);
    float s1 = gs1[idx], s2 = gs2[idx];
    float mean = s1 / cnt, ex2 = s2 / cnt;
    float ms = gn_ms_l[c];
    float var = ex2 - mean * mean * ms * (2.0f - ms);
    float inv = rsqrtf(fmaxf(var, 0.f) + 1e-6f);
    meanms[idx] = mean * ms;
    winv[idx]   = gn_w_l[c] * inv;
    gs1[idx] = 0.f; gs2[idx] = 0.f;   // reset for next layer
}

// ------------- fused: norm+relu+residual -> h, then next-layer GEMM ------------
__global__ __launch_bounds__(256) void k_upgemm(const u16* __restrict__ gbufb,
                                                const int* __restrict__ batch,
                                                const float* meanms, const float* winv,
                                                const float* gn_b_l, float* hout,
                                                const u16* wp_next, const float* comb_b_next,
                                                u16* basesb, u16* wcoefb){
    __shared__ u16 lA[16 * 136];
    int tid = threadIdx.x;
    int n0 = blockIdx.x * 16;
    {
        int c = tid & 127, half = tid >> 7;
        float gb = gn_b_l[c];
        for (int i = 0; i < 8; ++i){
            int r = i * 2 + half;
            int n = n0 + r;
            int bg = batch[n];
            float g = bf1(gbufb[(size_t)n * HIDC + c]);
            float val = fmaxf((g - meanms[bg * HIDC + c]) * winv[bg * HIDC + c] + gb, 0.f);
            float hn = hout[(size_t)n * HIDC + c] + val;
            hout[(size_t)n * HIDC + c] = hn;
            lA[r * 136 + c] = f2bf(hn);
        }
    }
    __syncthreads();

    int lane = tid & 63, wv = tid >> 6;
    int l15 = lane & 15, lhi = lane >> 4;
    const u16* ar = lA + l15 * 136;
    short8v b0 = *(const short8v*)(ar + lhi * 8);
    short8v b1 = *(const short8v*)(ar + 32 + lhi * 8);
    short8v b2 = *(const short8v*)(ar + 64 + lhi * 8);
    short8v b3 = *(const short8v*)(ar + 96 + lhi * 8);
    for (int ct = wv; ct < 10; ct += 4){
        const short8v* bp = ((const short8v*)wp_next) + ct * 256 + lane;
        f32x4 acc = {0.f, 0.f, 0.f, 0.f};
        acc = __builtin_amdgcn_mfma_f32_16x16x32_bf16(b0, bp[0],   acc, 0, 0, 0);
        acc = __builtin_amdgcn_mfma_f32_16x16x32_bf16(b1, bp[64],  acc, 0, 0, 0);
        acc = __builtin_amdgcn_mfma_f32_16x16x32_bf16(b2, bp[128], acc, 0, 0, 0);
        acc = __builtin_amdgcn_mfma_f32_16x16x32_bf16(b3, bp[192], acc, 0, 0, 0);
        int r0 = n0 + lhi * 4, col = ct * 16 + l15;
        if (ct < 4){
            for (int r = 0; r < 4; ++r)
                basesb[(size_t)(r0 + r) * 64 + col] = f2bf(acc[r]);
        } else {
            int c = col - 64;
            float bb = comb_b_next[c];
            for (int r = 0; r < 4; ++r)
                wcoefb[(size_t)(r0 + r) * 96 + c] = f2bf(acc[r] + bb);
        }
    }
}

// ------------- last layer: norm+relu+residual + mean-pool accumulation ---------
__global__ __launch_bounds__(256) void k_uplast(const u16* __restrict__ gbufb,
                                                const int* __restrict__ batch,
                                                const float* meanms, const float* winv,
                                                const float* gn_b_l, float* hout, float* ysum){
    int tid = threadIdx.x;
    int c = tid & 127, half = tid >> 7;
    int n0 = blockIdx.x * 8;
    float gb = gn_b_l[c];
    float accY = 0.f; int curG = -1;
    for (int i = 0; i < 4; ++i){
        int n = n0 + i * 2 + half;
        int bg = batch[n];
        float g = bf1(gbufb[(size_t)n * HIDC + c]);
        float val = fmaxf((g - meanms[bg * HIDC + c]) * winv[bg * HIDC + c] + gb, 0.f);
        float hn = hout[(size_t)n * HIDC + c] + val;
        hout[(size_t)n * HIDC + c] = hn;
        if (bg != curG){
            if (curG >= 0) atomicAdd(&ysum[curG * HIDC + c], accY);
            curG = bg; accY = 0.f;
        }
        accY += hn;
    }
    if (curG >= 0) atomicAdd(&ysum[curG * HIDC + c], accY);
}

__global__ __launch_bounds__(256) void k_yscale(float* y, const int* npg){
    int idx = blockIdx.x * 256 + threadIdx.x;  // 8192
    int bg = idx >> 7;
    y[idx] /= fmaxf((float)npg[bg], 1.0f);
}

// ---------------- launch ----------------
extern "C" void kernel_launch(void* const* d_in, const int* in_sizes, int n_in,
                              void* d_out, int out_size, void* d_ws, size_t ws_size,
                              hipStream_t stream){
    const float* x       = (const float*)d_in[0];
    const int*   ei      = (const int*)d_in[1];
    const int*   batch   = (const int*)d_in[2];
    const int*   npg     = (const int*)d_in[3];
    const float* lin_w   = (const float*)d_in[4];
    const float* lin_b   = (const float*)d_in[5];
    const float* bases_w = (const float*)d_in[6];
    const float* comb_w  = (const float*)d_in[7];
    const float* comb_b  = (const float*)d_in[8];
    const float* conv_b  = (const float*)d_in[9];
    const float* gn_w    = (const float*)d_in[10];
    const float* gn_b    = (const float*)d_in[11];
    const float* gn_ms   = (const float*)d_in[12];
    (void)in_sizes; (void)n_in; (void)out_size; (void)ws_size;

    float* hout = (float*)d_out;
    float* yout = hout + (size_t)NN * HIDC;

    char* basep = (char*)d_ws;
    size_t o = 0;
    auto alloc = [&](size_t bytes) -> char* {
        char* p = basep + o;
        o = (o + bytes + 255) & ~(size_t)255;
        return p;
    };
    u16*   wpack  = (u16*)  alloc((size_t)98304 * 2);
    u16*   basesb = (u16*)  alloc((size_t)NN * 64 * 2);
    u16*   wcoefb = (u16*)  alloc((size_t)NN * 96 * 2);
    u16*   gbufb  = (u16*)  alloc((size_t)NN * HIDC * 2);
    int*   deg    = (int*)  alloc((size_t)NN * 4);
    int*   rowptr = (int*)  alloc((size_t)(NN + 1) * 4);
    int*   fill   = (int*)  alloc((size_t)NN * 4);
    int*   ssrc   = (int*)  alloc((size_t)EE * 4);
    int*   bsums  = (int*)  alloc(128 * 4);
    int*   boffs  = (int*)  alloc(128 * 4);
    float* gs1    = (float*)alloc(8192 * 4);
    float* gs2    = (float*)alloc(8192 * 4);
    float* meanms = (float*)alloc(8192 * 4);
    float* winv   = (float*)alloc(8192 * 4);

    hipMemsetAsync(deg,  0, (size_t)NN * 4, stream);
    hipMemsetAsync(fill, 0, (size_t)NN * 4, stream);
    hipMemsetAsync(gs1,  0, (size_t)8192 * 4, stream);
    hipMemsetAsync(gs2,  0, (size_t)8192 * 4, stream);
    hipMemsetAsync(yout, 0, (size_t)8192 * 4, stream);

    k_pack   <<<384,  256, 0, stream>>>(lin_w, bases_w, comb_w, wpack);
    k_hist   <<<6250, 256, 0, stream>>>(ei + EE, deg);
    k_scan1  <<<98,   256, 0, stream>>>(deg, bsums);
    k_scan2  <<<1,    64,  0, stream>>>(bsums, boffs, 98);
    k_scan3  <<<98,   256, 0, stream>>>(deg, boffs, rowptr);
    k_scatter<<<6250, 256, 0, stream>>>(ei, ei + EE, rowptr, fill, ssrc);

    k_lin_gemm0<<<6250, 256, 0, stream>>>(x, wpack, lin_b, comb_b, hout, basesb, wcoefb);

    for (int l = 0; l < LL; ++l){
        k_aggcmb  <<<25000, 256, 0, stream>>>(basesb, rowptr, ssrc, wcoefb,
                                              conv_b + l * HIDC, gbufb);
        k_stats   <<<200,   256, 0, stream>>>(gbufb, batch, gs1, gs2);
        k_finalize<<<32,    256, 0, stream>>>(gs1, gs2, npg, gn_ms + l * HIDC,
                                              gn_w + l * HIDC, meanms, winv);
        if (l < 3){
            k_upgemm<<<6250, 256, 0, stream>>>(gbufb, batch, meanms, winv,
                                               gn_b + l * HIDC, hout,
                                               wpack + 16384 + (l + 1) * 20480,
                                               comb_b + (l + 1) * 96, basesb, wcoefb);
        } else {
            k_uplast<<<12500, 256, 0, stream>>>(gbufb, batch, meanms, winv,
                                                gn_b + l * HIDC, hout, yout);
        }
    }
    k_yscale<<<32, 256, 0, stream>>>(yout, npg);
}